// Round 13
// baseline (18.597 us; speedup 1.0000x reference)
//
#include <hip/hip_runtime.h>
#include <hip/hip_bf16.h>

typedef short short8 __attribute__((ext_vector_type(8)));
typedef float f32x4 __attribute__((ext_vector_type(4)));

// RNE f32->bf16 via hardware v_cvt_pk_bf16_f32 (HIP intrinsic, compiler-scheduled)
static __device__ __forceinline__ ushort2 pk2(float a, float b) {
    __hip_bfloat162 h = __float22bfloat162_rn(make_float2(a, b));
    ushort2 r;
    __builtin_memcpy(&r, &h, 4);
    return r;
}
static __device__ __forceinline__ unsigned short bf1(float a) {
    __hip_bfloat16 h = __float2bfloat16(a);
    unsigned short r;
    __builtin_memcpy(&r, &h, 2);
    return r;
}

// Single kernel, single launch. Block = (b, 64-px, 64-col) as R12 (16.3us), but
// 512 threads / 8 waves with SPLIT-K wave specialization (work-conserving
// occupancy doubling: 4 waves/SIMD instead of 2):
//   wave wh=0 (wl=0..3): full inj (E@We slice) + bounce + main GEMM ks 0..3
//   wave wh=1 (wl=0..3): main GEMM ks 4..7 immediately (overlaps wh0's inj)
// partial accumulators exchanged via Qbuf LDS at one extra barrier.
// Total VMEM/MFMA per block identical to R12.
__global__ __launch_bounds__(512)
void fused_all(const float* __restrict__ patches,
               const float* __restrict__ embs,
               const int* __restrict__ locations,
               const float* __restrict__ Wp,
               const float* __restrict__ We,
               float* __restrict__ out) {
    __shared__ __align__(16) unsigned short Ash[64 * 256];      // 32 KB, swizzled
    __shared__ __align__(16) unsigned short Ebf[16 * 256];      // 8 KB, swizzled
    __shared__ __align__(16) unsigned short injW[4 * 16 * 32];  // 4 KB
    __shared__ __align__(16) float Qbuf[2 * 4 * 64 * 8];        // 16 KB partials
    __shared__ unsigned maskL[64];
    __shared__ float rcL[64];

    const int bid = blockIdx.x, t = threadIdx.x;
    const int b = bid >> 6, pt = (bid >> 2) & 15, ct = bid & 3;
    const int p0 = pt * 64, c0 = ct * 64;
    const int w = t >> 6, wh = w >> 2, wl = w & 3;
    const int lane = t & 63, lhi = lane >> 4, llo = lane & 15;
    const int oc = c0 + wl * 16 + llo;   // output column this lane owns

    // ---- A staging: patches[b, p0..p0+64, :] -> bf16 LDS, XOR-swizzled ----
    const float* pbase = patches + (size_t)(b * 1024 + p0) * 256;
    #pragma unroll
    for (int it = 0; it < 8; ++it) {
        int u = t + it * 512;
        int row = u >> 6, c4 = u & 63;
        float4 f = *reinterpret_cast<const float4*>(pbase + row * 256 + c4 * 4);
        ushort2 lo = pk2(f.x, f.y), hi = pk2(f.z, f.w);
        ushort4 o = {lo.x, lo.y, hi.x, hi.y};
        int byte = row * 512 + ((c4 * 8) ^ ((row & 7) << 4));
        *reinterpret_cast<ushort4*>(reinterpret_cast<char*>(Ash) + byte) = o;
    }

    // ---- E staging: rows 0..14 bf16 swizzled + f32-accurate mean row 15 ----
    if (t < 128) {
        const int c0e = t * 2;
        float s0 = 0.f, s1 = 0.f;
        #pragma unroll
        for (int r = 0; r < 15; ++r) {
            float2 v = *reinterpret_cast<const float2*>(embs + (size_t)(b * 15 + r) * 256 + c0e);
            s0 += v.x; s1 += v.y;
            ushort2 p2 = pk2(v.x, v.y);
            unsigned pk = (unsigned)p2.x | ((unsigned)p2.y << 16);
            *reinterpret_cast<unsigned*>(reinterpret_cast<char*>(Ebf)
                + r * 512 + ((c0e * 2) ^ ((r & 7) << 4))) = pk;
        }
        ushort2 p2 = pk2(s0 * (1.0f / 15.0f), s1 * (1.0f / 15.0f));
        unsigned pk = (unsigned)p2.x | ((unsigned)p2.y << 16);
        *reinterpret_cast<unsigned*>(reinterpret_cast<char*>(Ebf)
            + 15 * 512 + ((c0e * 2) ^ (7 << 4))) = pk;
    }

    // ---- masks + 1/cnt for the 64 pixels ----
    if (t < 64) {
        int p = p0 + t;
        int h = p >> 5, wpx = p & 31;
        const int* loc = locations + b * 60;
        unsigned m = 1u << 15;  // full-image box always contains
        #pragma unroll
        for (int nb = 0; nb < 15; ++nb) {
            int y0 = loc[nb * 4 + 0] & ~1;
            int x0 = loc[nb * 4 + 1] & ~1;
            int y1 = (loc[nb * 4 + 2] & ~1) + 2;
            int x1 = (loc[nb * 4 + 3] & ~1) + 2;
            if (h >= y0 && h < y1 && wpx >= x0 && wpx < x1) m |= 1u << nb;
        }
        maskL[t] = m;
        rcL[t] = 1.0f / (float)__popc(m);
    }
    __syncthreads();   // barrier 1: staging complete

    short8 jf;
    f32x4 acc[4];
    #pragma unroll
    for (int mt = 0; mt < 4; ++mt) acc[mt] = (f32x4){0.f, 0.f, 0.f, 0.f};

    if (wh == 0) {
        // ---- full inj slice: (E_ext @ We)[:, oc] via MFMA ----
        f32x4 accI = (f32x4){0.f, 0.f, 0.f, 0.f};
        #pragma unroll
        for (int ks = 0; ks < 8; ++ks) {
            const short8 afr = *reinterpret_cast<const short8*>(
                reinterpret_cast<const char*>(Ebf)
                + llo * 512 + ((ks * 64 + lhi * 16) ^ ((llo & 7) << 4)));
            short8 bfr;
            #pragma unroll
            for (int rr = 0; rr < 4; ++rr) {
                float w0 = We[(size_t)(ks * 32 + lhi * 8 + 2 * rr + 0) * 256 + oc];
                float w1 = We[(size_t)(ks * 32 + lhi * 8 + 2 * rr + 1) * 256 + oc];
                ushort2 p2 = pk2(w0, w1);
                bfr[2 * rr + 0] = (short)p2.x;
                bfr[2 * rr + 1] = (short)p2.y;
            }
            accI = __builtin_amdgcn_mfma_f32_16x16x32_bf16(afr, bfr, accI, 0, 0, 0);
        }
        // bounce to injW [col][n] bf16 (+ zero-pad n=16..31)
        ushort2 lo = pk2(accI[0], accI[1]), hi = pk2(accI[2], accI[3]);
        ushort4 o4 = {lo.x, lo.y, hi.x, hi.y};
        unsigned short* dst = injW + wl * 512 + llo * 32;
        *reinterpret_cast<ushort4*>(dst + lhi * 4) = o4;
        ushort4 z = {0, 0, 0, 0};
        *reinterpret_cast<ushort4*>(dst + 16 + lhi * 4) = z;
        asm volatile("s_waitcnt lgkmcnt(0)" ::: "memory");
        __builtin_amdgcn_sched_barrier(0);
        jf = *reinterpret_cast<const short8*>(injW + wl * 512 + llo * 32 + lhi * 8);
    }

    // ---- main GEMM partial: this wave's 4 k-steps, all 4 pixel-groups ----
    #pragma unroll
    for (int ks2 = 0; ks2 < 4; ++ks2) {
        const int ks = wh * 4 + ks2;
        short8 bfr;
        #pragma unroll
        for (int rr = 0; rr < 4; ++rr) {
            float w0 = Wp[(size_t)(ks * 32 + lhi * 8 + 2 * rr + 0) * 256 + oc];
            float w1 = Wp[(size_t)(ks * 32 + lhi * 8 + 2 * rr + 1) * 256 + oc];
            ushort2 p2 = pk2(w0, w1);
            bfr[2 * rr + 0] = (short)p2.x;
            bfr[2 * rr + 1] = (short)p2.y;
        }
        #pragma unroll
        for (int mt = 0; mt < 4; ++mt) {
            int row = mt * 16 + llo;
            const short8 af = *reinterpret_cast<const short8*>(
                reinterpret_cast<const char*>(Ash)
                + row * 512 + (((ks * 32 + lhi * 8) * 2) ^ ((row & 7) << 4)));
            acc[mt] = __builtin_amdgcn_mfma_f32_16x16x32_bf16(af, bfr, acc[mt], 0, 0, 0);
        }
    }

    // ---- exchange partials: wh0 ships mt2,3 (slot1); wh1 ships mt0,1 (slot0) ----
    {
        float* qp = Qbuf + (((wh ^ 1) * 4 + wl) * 64 + lane) * 8;
        const int mtb = (wh == 0) ? 2 : 0;
        *reinterpret_cast<f32x4*>(qp + 0) = acc[mtb + 0];
        *reinterpret_cast<f32x4*>(qp + 4) = acc[mtb + 1];
    }
    __syncthreads();   // barrier 2: partials + injW visible

    if (wh == 1)
        jf = *reinterpret_cast<const short8*>(injW + wl * 512 + llo * 32 + lhi * 8);

    // ---- combine + rc-folded mask-MFMA epilogue + store (2 mt per wave) ----
    const float* qr = Qbuf + ((wh * 4 + wl) * 64 + lane) * 8;
    const int mtbase = wh * 2;
    #pragma unroll
    for (int i = 0; i < 2; ++i) {
        const int mt = mtbase + i;
        f32x4 part = *reinterpret_cast<const f32x4*>(qr + i * 4);
        f32x4 tot = acc[mt] + part;
        unsigned m = maskL[mt * 16 + llo];
        unsigned short rcb = bf1(rcL[mt * 16 + llo]);
        short8 mfrag;
        #pragma unroll
        for (int r = 0; r < 8; ++r) {
            int k = lhi * 8 + r;
            mfrag[r] = (k < 16 && ((m >> k) & 1u)) ? (short)rcb : (short)0;
        }
        f32x4 accE = __builtin_amdgcn_mfma_f32_16x16x32_bf16(
            mfrag, jf, (f32x4){0.f, 0.f, 0.f, 0.f}, 0, 0, 0);
        float* ob = out + (size_t)(b * 1024 + p0 + mt * 16) * 256;
        #pragma unroll
        for (int j = 0; j < 4; ++j)
            ob[(lhi * 4 + j) * 256 + oc] = tot[j] + accE[j];
    }
}

extern "C" void kernel_launch(void* const* d_in, const int* in_sizes, int n_in,
                              void* d_out, int out_size, void* d_ws, size_t ws_size,
                              hipStream_t stream) {
    const float* patches = (const float*)d_in[0];
    const float* embs    = (const float*)d_in[1];
    const int*   locs    = (const int*)d_in[2];
    const float* Wp      = (const float*)d_in[3];
    const float* We      = (const float*)d_in[4];
    float* out = (float*)d_out;

    fused_all<<<512, 512, 0, stream>>>(patches, embs, locs, Wp, We, out);
}

// Round 14
// 16.192 us; speedup vs baseline: 1.1485x; 1.1485x over previous
//
#include <hip/hip_runtime.h>
#include <hip/hip_bf16.h>

typedef short short8 __attribute__((ext_vector_type(8)));
typedef float f32x4 __attribute__((ext_vector_type(4)));

// RNE f32->bf16 via hardware v_cvt_pk_bf16_f32 (HIP intrinsic, compiler-scheduled)
static __device__ __forceinline__ ushort2 pk2(float a, float b) {
    __hip_bfloat162 h = __float22bfloat162_rn(make_float2(a, b));
    ushort2 r;
    __builtin_memcpy(&r, &h, 4);
    return r;
}
static __device__ __forceinline__ unsigned short bf1(float a) {
    __hip_bfloat16 h = __float2bfloat16(a);
    unsigned short r;
    __builtin_memcpy(&r, &h, 2);
    return r;
}

// Single kernel, single launch (R12 structure, 16.3us) minus the inj->jf LDS
// bounce: the rearrangement is a pure intra-wave permutation, done with 4
// ds_bpermute ops. No lgkmcnt(0) fence, no sched_barrier -> compiler can
// pipeline Wp gathers under the inj phase. jf for lhi>=2 is garbage-but-finite
// (wrapped lanes) and multiplied by mfrag=0, so results are bit-identical.
// Block = (b, 64-px, 64-col), 4 waves; ONE __syncthreads; no workspace.
__global__ __launch_bounds__(256)
void fused_all(const float* __restrict__ patches,
               const float* __restrict__ embs,
               const int* __restrict__ locations,
               const float* __restrict__ Wp,
               const float* __restrict__ We,
               float* __restrict__ out) {
    __shared__ __align__(16) unsigned short Ash[64 * 256];    // 32 KB, swizzled
    __shared__ __align__(16) unsigned short Ebf[16 * 256];    // 8 KB, swizzled
    __shared__ unsigned maskL[64];
    __shared__ float rcL[64];

    const int bid = blockIdx.x, t = threadIdx.x;
    const int b = bid >> 6, pt = (bid >> 2) & 15, ct = bid & 3;
    const int p0 = pt * 64, c0 = ct * 64;
    const int wv = t >> 6, lane = t & 63, lhi = lane >> 4, llo = lane & 15;
    const int oc = c0 + wv * 16 + llo;   // output column this lane owns

    // ---- A staging: patches[b, p0..p0+64, :] -> bf16 LDS, XOR-swizzled rows ----
    const float* pbase = patches + (size_t)(b * 1024 + p0) * 256;
    #pragma unroll
    for (int it = 0; it < 16; ++it) {
        int u = t + it * 256;
        int row = u >> 6, c4 = u & 63;
        float4 f = *reinterpret_cast<const float4*>(pbase + row * 256 + c4 * 4);
        ushort2 lo = pk2(f.x, f.y), hi = pk2(f.z, f.w);
        ushort4 o = {lo.x, lo.y, hi.x, hi.y};
        int byte = row * 512 + ((c4 * 8) ^ ((row & 7) << 4));
        *reinterpret_cast<ushort4*>(reinterpret_cast<char*>(Ash) + byte) = o;
    }

    // ---- E staging: embs rows 0..14 (bf16, swizzled) + f32-accurate mean row 15 ----
    if (t < 128) {
        const int c0e = t * 2;
        float s0 = 0.f, s1 = 0.f;
        #pragma unroll
        for (int r = 0; r < 15; ++r) {
            float2 v = *reinterpret_cast<const float2*>(embs + (size_t)(b * 15 + r) * 256 + c0e);
            s0 += v.x; s1 += v.y;
            ushort2 p2 = pk2(v.x, v.y);
            unsigned pk = (unsigned)p2.x | ((unsigned)p2.y << 16);
            *reinterpret_cast<unsigned*>(reinterpret_cast<char*>(Ebf)
                + r * 512 + ((c0e * 2) ^ ((r & 7) << 4))) = pk;
        }
        ushort2 p2 = pk2(s0 * (1.0f / 15.0f), s1 * (1.0f / 15.0f));
        unsigned pk = (unsigned)p2.x | ((unsigned)p2.y << 16);
        *reinterpret_cast<unsigned*>(reinterpret_cast<char*>(Ebf)
            + 15 * 512 + ((c0e * 2) ^ (7 << 4))) = pk;
    }

    // ---- masks + 1/cnt for the 64 pixels ----
    if (t < 64) {
        int p = p0 + t;
        int h = p >> 5, w = p & 31;
        const int* loc = locations + b * 60;
        unsigned m = 1u << 15;  // full-image box always contains
        #pragma unroll
        for (int nb = 0; nb < 15; ++nb) {
            int y0 = loc[nb * 4 + 0] & ~1;
            int x0 = loc[nb * 4 + 1] & ~1;
            int y1 = (loc[nb * 4 + 2] & ~1) + 2;
            int x1 = (loc[nb * 4 + 3] & ~1) + 2;
            if (h >= y0 && h < y1 && w >= x0 && w < x1) m |= 1u << nb;
        }
        maskL[t] = m;
        rcL[t] = 1.0f / (float)__popc(m);
    }
    __syncthreads();   // the ONLY block barrier

    // ---- inj slice: (E_ext @ We)[:, oc] via MFMA (wave-private) ----
    f32x4 accI = (f32x4){0.f, 0.f, 0.f, 0.f};
    #pragma unroll
    for (int ks = 0; ks < 8; ++ks) {
        const short8 afr = *reinterpret_cast<const short8*>(
            reinterpret_cast<const char*>(Ebf)
            + llo * 512 + ((ks * 64 + lhi * 16) ^ ((llo & 7) << 4)));
        short8 bfr;
        #pragma unroll
        for (int rr = 0; rr < 4; ++rr) {
            float w0 = We[(size_t)(ks * 32 + lhi * 8 + 2 * rr + 0) * 256 + oc];
            float w1 = We[(size_t)(ks * 32 + lhi * 8 + 2 * rr + 1) * 256 + oc];
            ushort2 p2 = pk2(w0, w1);
            bfr[2 * rr + 0] = (short)p2.x;
            bfr[2 * rr + 1] = (short)p2.y;
        }
        accI = __builtin_amdgcn_mfma_f32_16x16x32_bf16(afr, bfr, accI, 0, 0, 0);
    }
    // ---- inj C-layout -> jf B-fragment via intra-wave permute (no LDS) ----
    // lane(llo,lhi) holds inj[n=lhi*4+j][oc]; jf[r]=inj[n=lhi*8+r][oc] lives in
    // lanes llo+32*lhi (r=0..3) and llo+32*lhi+16 (r=4..7). lhi>=2 wraps ->
    // finite garbage, masked by mfrag=0.
    short8 jf;
    {
        ushort2 plo = pk2(accI[0], accI[1]);
        ushort2 phi = pk2(accI[2], accI[3]);
        int q0 = (int)((unsigned)plo.x | ((unsigned)plo.y << 16));
        int q1 = (int)((unsigned)phi.x | ((unsigned)phi.y << 16));
        int a0 = (llo + 32 * lhi) << 2;
        union { short8 s; int i[4]; } J;
        J.i[0] = __builtin_amdgcn_ds_bpermute(a0, q0);
        J.i[1] = __builtin_amdgcn_ds_bpermute(a0, q1);
        J.i[2] = __builtin_amdgcn_ds_bpermute(a0 + 64, q0);
        J.i[3] = __builtin_amdgcn_ds_bpermute(a0 + 64, q1);
        jf = J.s;
    }

    // ---- main GEMM: 4 pixel-groups x 8 k-steps; B gathered from Wp (L2) ----
    f32x4 acc[4];
    #pragma unroll
    for (int mt = 0; mt < 4; ++mt) acc[mt] = (f32x4){0.f, 0.f, 0.f, 0.f};
    #pragma unroll
    for (int ks = 0; ks < 8; ++ks) {
        short8 bfr;
        #pragma unroll
        for (int rr = 0; rr < 4; ++rr) {
            float w0 = Wp[(size_t)(ks * 32 + lhi * 8 + 2 * rr + 0) * 256 + oc];
            float w1 = Wp[(size_t)(ks * 32 + lhi * 8 + 2 * rr + 1) * 256 + oc];
            ushort2 p2 = pk2(w0, w1);
            bfr[2 * rr + 0] = (short)p2.x;
            bfr[2 * rr + 1] = (short)p2.y;
        }
        #pragma unroll
        for (int mt = 0; mt < 4; ++mt) {
            int row = mt * 16 + llo;
            const short8 af = *reinterpret_cast<const short8*>(
                reinterpret_cast<const char*>(Ash)
                + row * 512 + (((ks * 32 + lhi * 8) * 2) ^ ((row & 7) << 4)));
            acc[mt] = __builtin_amdgcn_mfma_f32_16x16x32_bf16(af, bfr, acc[mt], 0, 0, 0);
        }
    }

    // ---- epilogue: rc-folded mask MFMA per pixel-group, then store ----
    #pragma unroll
    for (int mt = 0; mt < 4; ++mt) {
        unsigned m = maskL[mt * 16 + llo];
        unsigned short rcb = bf1(rcL[mt * 16 + llo]);
        short8 mfrag;
        #pragma unroll
        for (int r = 0; r < 8; ++r) {
            int k = lhi * 8 + r;
            mfrag[r] = (k < 16 && ((m >> k) & 1u)) ? (short)rcb : (short)0;
        }
        f32x4 accE = __builtin_amdgcn_mfma_f32_16x16x32_bf16(
            mfrag, jf, (f32x4){0.f, 0.f, 0.f, 0.f}, 0, 0, 0);
        float* ob = out + (size_t)(b * 1024 + p0 + mt * 16) * 256;
        #pragma unroll
        for (int j = 0; j < 4; ++j)
            ob[(lhi * 4 + j) * 256 + oc] = acc[mt][j] + accE[j];
    }
}

extern "C" void kernel_launch(void* const* d_in, const int* in_sizes, int n_in,
                              void* d_out, int out_size, void* d_ws, size_t ws_size,
                              hipStream_t stream) {
    const float* patches = (const float*)d_in[0];
    const float* embs    = (const float*)d_in[1];
    const int*   locs    = (const int*)d_in[2];
    const float* Wp      = (const float*)d_in[3];
    const float* We      = (const float*)d_in[4];
    float* out = (float*)d_out;

    fused_all<<<512, 256, 0, stream>>>(patches, embs, locs, Wp, We, out);
}